// Round 6
// baseline (484.252 us; speedup 1.0000x reference)
//
#include <hip/hip_runtime.h>
#include <hip/hip_bf16.h>

// GraphSAGE R11: port the R10 occupancy tile to gemm1 + raise fused bound.
//  gemm1: 64->32 rows/block (acc[2][4]=32 AGPR, 5KB LDS, ~55 VGPR est.)
//         -> 8 waves/SIMD reachable (was 3-wave/128-reg tile at 30% occ).
//  fused: launch_bounds(256,6->8); VGPR=40 < 64=512/8 and LDS 16KB*8 fits,
//         so 8 blocks/CU is legal. Spill falsifier: WRITE_SIZE >> 75MB.
//  Keeps: quad-coalesced gather, fragment-swizzled B (L2-hot, no B LDS),
//  XOR-swizzled A LDS, barrier-free fused k-loop, pipelined gemm1 staging.

constexpr int N_NODES = 100000;
constexpr int FANOUT  = 16;

typedef __attribute__((ext_vector_type(8))) short short8;
typedef __attribute__((ext_vector_type(4))) float f32x4;

__device__ inline unsigned short bf16_rne(float f) {
    unsigned u = __float_as_uint(f);
    return (unsigned short)((u + 0x7fffu + ((u >> 16) & 1u)) >> 16);
}
__device__ inline float bf16_tof(unsigned short s) {
    return __uint_as_float(((unsigned)s) << 16);
}

// ---- weights -> hi/lo bf16, FRAGMENT-SWIZZLED layout ----
// off(c,k) = ((tk*(C/16)+tc)*64 + qk*16 + mlc)*8 + e
//   tc=c>>4, mlc=c&15, tk=k>>5, qk=(k>>3)&3, e=k&7
__global__ __launch_bounds__(256)
void prep_Bsw(const float* __restrict__ W, unsigned short* __restrict__ Bhi,
              unsigned short* __restrict__ Blo, int D_IN, int D_OUT)
{
    int i = blockIdx.x * 256 + threadIdx.x;
    int total = 2 * D_OUT * D_IN;
    if (i >= total) return;
    int K = D_IN, C = 2 * D_OUT;
    int c = i / K, k = i % K;
    float v = (c < D_OUT) ? W[(size_t)c * (2 * K) + k]
                          : W[(size_t)(c - D_OUT) * (2 * K) + K + k];
    int tc = c >> 4, mlc = c & 15;
    int tk = k >> 5, qk = (k >> 3) & 3, e = k & 7;
    size_t off = ((size_t)(tk * (C / 16) + tc) * 64 + qk * 16 + mlc) * 8 + e;
    unsigned short hi = bf16_rne(v);
    Bhi[off] = hi;
    Blo[off] = bf16_rne(v - bf16_tof(hi));
}

// ---- gemm1: dense, K=256, C=256. block = 32 nodes, wave tile 32x64. ----
// R10-style small tile: acc[2][4]=32 AGPR, 5KB LDS, pipelined A staging,
// fragment-swizzled B from L2.
__global__ __launch_bounds__(256, 6)
void gemm1(const float* __restrict__ hf,
           const unsigned short* __restrict__ Bhi,
           const unsigned short* __restrict__ Blo,
           float* __restrict__ gs, unsigned short* __restrict__ gn, int N)
{
    constexpr int K = 256, DO = 128, LDA = 40;
    __shared__ unsigned short Ah[32 * LDA], Al[32 * LDA];

    const int tid  = threadIdx.x;
    const int wave = tid >> 6;
    const int lane = tid & 63;
    const int ml   = lane & 15;
    const int quad = lane >> 4;
    const int node0 = blockIdx.x * 32;

    // staging: thread t covers row (tid>>3), float4 chunk (tid&7) of the k-tile
    const int srow = tid >> 3;
    const int sc4  = tid & 7;
    int nd = node0 + srow; if (nd >= N) nd = N - 1;
    const float* pA = &hf[(size_t)nd * K + sc4 * 4];

    f32x4 acc[2][4];
    #pragma unroll
    for (int mi = 0; mi < 2; ++mi)
        #pragma unroll
        for (int ni = 0; ni < 4; ++ni)
            acc[mi][ni] = (f32x4){0.f, 0.f, 0.f, 0.f};

    float4 pf = *(const float4*)&pA[0];

    for (int k0 = 0; k0 < K; k0 += 32) {
        {
            float vv[4] = {pf.x, pf.y, pf.z, pf.w};
            unsigned short hi[4], lo[4];
            #pragma unroll
            for (int e = 0; e < 4; ++e) {
                hi[e] = bf16_rne(vv[e]);
                lo[e] = bf16_rne(vv[e] - bf16_tof(hi[e]));
            }
            *(uint2*)&Ah[srow * LDA + sc4 * 4] = *(const uint2*)hi;
            *(uint2*)&Al[srow * LDA + sc4 * 4] = *(const uint2*)lo;
        }
        if (k0 + 32 < K) pf = *(const float4*)&pA[k0 + 32];
        __syncthreads();

        short8 afh[2], afl[2];
        #pragma unroll
        for (int mi = 0; mi < 2; ++mi) {
            int r = mi * 16 + ml;
            afh[mi] = *(const short8*)&Ah[r * LDA + quad * 8];
            afl[mi] = *(const short8*)&Al[r * LDA + quad * 8];
        }
        const size_t bbase = (size_t)((k0 >> 5) * 16 + wave * 4) * 512 + (size_t)lane * 8;
        #pragma unroll
        for (int ni = 0; ni < 4; ++ni) {
            short8 bh = *(const short8*)&Bhi[bbase + ni * 512];
            short8 bl = *(const short8*)&Blo[bbase + ni * 512];
            #pragma unroll
            for (int mi = 0; mi < 2; ++mi) {
                acc[mi][ni] = __builtin_amdgcn_mfma_f32_16x16x32_bf16(afl[mi], bh, acc[mi][ni], 0, 0, 0);
                acc[mi][ni] = __builtin_amdgcn_mfma_f32_16x16x32_bf16(afh[mi], bl, acc[mi][ni], 0, 0, 0);
                acc[mi][ni] = __builtin_amdgcn_mfma_f32_16x16x32_bf16(afh[mi], bh, acc[mi][ni], 0, 0, 0);
            }
        }
        __syncthreads();
    }

    #pragma unroll
    for (int mi = 0; mi < 2; ++mi)
        #pragma unroll
        for (int r = 0; r < 4; ++r) {
            int node = node0 + mi * 16 + quad * 4 + r;
            if (node >= N) continue;
            #pragma unroll
            for (int ni = 0; ni < 4; ++ni) {
                int c = wave * 64 + ni * 16 + ml;
                float v = acc[mi][ni][r];
                if (c < DO) gs[(size_t)node * DO + c] = v;
                else        gn[(size_t)node * DO + (c - DO)] = bf16_rne(v);
            }
        }
}

// ---- fused layer: 32 nodes/block, 8-waves/SIMD target ----
// D_IN=128 fixed. C=256 (DO=128, NI=4) or C=128 (DO=64, NI=2).
template<int C>
__global__ __launch_bounds__(256, 8)
void fused_layer(const float* __restrict__ gs_in,
                 const unsigned short* __restrict__ gn_in,
                 const int* __restrict__ neigh,
                 const unsigned short* __restrict__ Bhi,
                 const unsigned short* __restrict__ Blo,
                 float* __restrict__ gs_out,
                 unsigned short* __restrict__ gn_out, int N)
{
    constexpr int K = 128, DO = C / 2, NI = C / 64;
    __shared__ unsigned short Afh[32 * 128], Afl[32 * 128];   // 16384 B total

    const int tid  = threadIdx.x;
    const int wave = tid >> 6;
    const int lane = tid & 63;
    const int ml   = lane & 15;
    const int quad = lane >> 4;
    const int node0 = blockIdx.x * 32;

    // ---- A-phase: h = relu(gs + mean*gn[nb]); 8 threads/row, thread s
    // owns chunks c0=64(s>>2)+8(s&3) and c1=c0+32 -> each quad load
    // instruction covers one full 64B line of the neighbor row.
    {
        const int row = tid >> 3;          // node within block (0..31)
        const int s   = tid & 7;
        const int c0  = 64 * (s >> 2) + 8 * (s & 3);
        const int c1  = c0 + 32;
        int nd = node0 + row; if (nd >= N) nd = N - 1;
        const int4* nb4 = (const int4*)(neigh + (size_t)nd * FANOUT);
        int4 q0 = nb4[0], q1 = nb4[1], q2 = nb4[2], q3 = nb4[3];
        int ids[FANOUT] = {q0.x, q0.y, q0.z, q0.w, q1.x, q1.y, q1.z, q1.w,
                           q2.x, q2.y, q2.z, q2.w, q3.x, q3.y, q3.z, q3.w};
        float acc[16];
        #pragma unroll
        for (int c = 0; c < 16; ++c) acc[c] = 0.f;
        #pragma unroll
        for (int j = 0; j < FANOUT; ++j) {
            const uint4* src = (const uint4*)&gn_in[(size_t)ids[j] * 128];
            uint4 qa = src[c0 >> 3];
            uint4 qb = src[c1 >> 3];
            acc[0]  += __uint_as_float(qa.x << 16);
            acc[1]  += __uint_as_float(qa.x & 0xffff0000u);
            acc[2]  += __uint_as_float(qa.y << 16);
            acc[3]  += __uint_as_float(qa.y & 0xffff0000u);
            acc[4]  += __uint_as_float(qa.z << 16);
            acc[5]  += __uint_as_float(qa.z & 0xffff0000u);
            acc[6]  += __uint_as_float(qa.w << 16);
            acc[7]  += __uint_as_float(qa.w & 0xffff0000u);
            acc[8]  += __uint_as_float(qb.x << 16);
            acc[9]  += __uint_as_float(qb.x & 0xffff0000u);
            acc[10] += __uint_as_float(qb.y << 16);
            acc[11] += __uint_as_float(qb.y & 0xffff0000u);
            acc[12] += __uint_as_float(qb.z << 16);
            acc[13] += __uint_as_float(qb.z & 0xffff0000u);
            acc[14] += __uint_as_float(qb.w << 16);
            acc[15] += __uint_as_float(qb.w & 0xffff0000u);
        }
        const float inv = 1.0f / (float)FANOUT;
        const float* gsp = &gs_in[(size_t)nd * 128];
        #pragma unroll
        for (int cc = 0; cc < 2; ++cc) {
            const int ch = cc ? c1 : c0;
            float4 g0 = *(const float4*)&gsp[ch];
            float4 g1 = *(const float4*)&gsp[ch + 4];
            float sv[8] = {g0.x, g0.y, g0.z, g0.w, g1.x, g1.y, g1.z, g1.w};
            alignas(16) unsigned short th[8], tl[8];
            #pragma unroll
            for (int e = 0; e < 8; ++e) {
                float h = fmaxf(fmaf(acc[cc * 8 + e], inv, sv[e]), 0.f);
                unsigned short hi = bf16_rne(h);
                th[e] = hi;
                tl[e] = bf16_rne(h - bf16_tof(hi));
            }
            int soff = (row * 128 + ch) ^ ((row & 7) << 3);
            *(uint4*)&Afh[soff] = *(const uint4*)th;
            *(uint4*)&Afl[soff] = *(const uint4*)tl;
        }
    }
    __syncthreads();

    f32x4 acc[2][NI];
    #pragma unroll
    for (int mi = 0; mi < 2; ++mi)
        #pragma unroll
        for (int ni = 0; ni < NI; ++ni)
            acc[mi][ni] = (f32x4){0.f, 0.f, 0.f, 0.f};

    // barrier-free k-loop: A from swizzled LDS, B fragment-swizzled global
    for (int k0 = 0; k0 < K; k0 += 32) {
        short8 afh[2], afl[2];
        #pragma unroll
        for (int mi = 0; mi < 2; ++mi) {
            int r = mi * 16 + ml;
            int soff = (r * 128 + k0 + quad * 8) ^ ((r & 7) << 3);
            afh[mi] = *(const short8*)&Afh[soff];
            afl[mi] = *(const short8*)&Afl[soff];
        }
        const size_t bbase = (size_t)((k0 >> 5) * (C / 16) + wave * NI) * 512 + (size_t)lane * 8;
        #pragma unroll
        for (int ni = 0; ni < NI; ++ni) {
            short8 bh = *(const short8*)&Bhi[bbase + ni * 512];
            short8 bl = *(const short8*)&Blo[bbase + ni * 512];
            #pragma unroll
            for (int mi = 0; mi < 2; ++mi) {
                acc[mi][ni] = __builtin_amdgcn_mfma_f32_16x16x32_bf16(afl[mi], bh, acc[mi][ni], 0, 0, 0);
                acc[mi][ni] = __builtin_amdgcn_mfma_f32_16x16x32_bf16(afh[mi], bl, acc[mi][ni], 0, 0, 0);
                acc[mi][ni] = __builtin_amdgcn_mfma_f32_16x16x32_bf16(afh[mi], bh, acc[mi][ni], 0, 0, 0);
            }
        }
    }

    #pragma unroll
    for (int mi = 0; mi < 2; ++mi)
        #pragma unroll
        for (int r = 0; r < 4; ++r) {
            int node = node0 + mi * 16 + quad * 4 + r;
            if (node >= N) continue;
            #pragma unroll
            for (int ni = 0; ni < NI; ++ni) {
                int c = wave * (16 * NI) + ni * 16 + ml;
                float v = acc[mi][ni][r];
                if (c < DO) gs_out[(size_t)node * DO + c] = v;
                else        gn_out[(size_t)node * DO + (c - DO)] = bf16_rne(v);
            }
        }
}

// ---- final: out[i] = relu(gs4[nodes[i]] + mean_j gn4[nb[j]]), D_OUT=64 ----
__global__ __launch_bounds__(256)
void agg_out(const float* __restrict__ gs4, const unsigned short* __restrict__ gn4,
             const int* __restrict__ neigh, const int* __restrict__ nodes,
             float* __restrict__ out, int N)
{
    const int i    = blockIdx.x * 32 + (threadIdx.x >> 3);
    const int lane = threadIdx.x & 7;
    if (i >= N) return;
    const int nd = nodes[i];
    const int4* nb4 = (const int4*)(neigh + (size_t)nd * FANOUT);
    int4 q0 = nb4[0], q1 = nb4[1], q2 = nb4[2], q3 = nb4[3];
    int ids[FANOUT] = {q0.x, q0.y, q0.z, q0.w, q1.x, q1.y, q1.z, q1.w,
                       q2.x, q2.y, q2.z, q2.w, q3.x, q3.y, q3.z, q3.w};
    float acc[8];
    #pragma unroll
    for (int c = 0; c < 8; ++c) acc[c] = 0.f;
    #pragma unroll
    for (int j = 0; j < FANOUT; ++j) {
        uint4 q = *(const uint4*)&gn4[(size_t)ids[j] * 64 + lane * 8];
        acc[0] += __uint_as_float(q.x << 16);
        acc[1] += __uint_as_float(q.x & 0xffff0000u);
        acc[2] += __uint_as_float(q.y << 16);
        acc[3] += __uint_as_float(q.y & 0xffff0000u);
        acc[4] += __uint_as_float(q.z << 16);
        acc[5] += __uint_as_float(q.z & 0xffff0000u);
        acc[6] += __uint_as_float(q.w << 16);
        acc[7] += __uint_as_float(q.w & 0xffff0000u);
    }
    const float inv = 1.0f / (float)FANOUT;
    const float* s = gs4 + (size_t)nd * 64 + lane * 8;
    float4 s0 = *(const float4*)&s[0];
    float4 s1 = *(const float4*)&s[4];
    float4 o0, o1;
    o0.x = fmaxf(fmaf(acc[0], inv, s0.x), 0.f);
    o0.y = fmaxf(fmaf(acc[1], inv, s0.y), 0.f);
    o0.z = fmaxf(fmaf(acc[2], inv, s0.z), 0.f);
    o0.w = fmaxf(fmaf(acc[3], inv, s0.w), 0.f);
    o1.x = fmaxf(fmaf(acc[4], inv, s1.x), 0.f);
    o1.y = fmaxf(fmaf(acc[5], inv, s1.y), 0.f);
    o1.z = fmaxf(fmaf(acc[6], inv, s1.z), 0.f);
    o1.w = fmaxf(fmaf(acc[7], inv, s1.w), 0.f);
    float* op = out + (size_t)i * 64 + lane * 8;
    *(float4*)&op[0] = o0;
    *(float4*)&op[4] = o1;
}

extern "C" void kernel_launch(void* const* d_in, const int* in_sizes, int n_in,
                              void* d_out, int out_size, void* d_ws, size_t ws_size,
                              hipStream_t stream)
{
    const float* features = (const float*)d_in[0];
    const float* W1       = (const float*)d_in[1];
    const float* W2       = (const float*)d_in[2];
    const float* W3       = (const float*)d_in[3];
    const float* W4       = (const float*)d_in[4];
    const int*   nodes    = (const int*)d_in[5];
    const int*   neigh    = (const int*)d_in[6];
    float*       out      = (float*)d_out;

    unsigned short* B1h = (unsigned short*)d_ws;       // 65536
    unsigned short* B1l = B1h + 65536;
    unsigned short* B2h = B1l + 65536;                 // 32768
    unsigned short* B2l = B2h + 32768;
    unsigned short* B3h = B2l + 32768;
    unsigned short* B3l = B3h + 32768;
    unsigned short* B4h = B3l + 32768;                 // 16384
    unsigned short* B4l = B4h + 16384;
    float* gs = (float*)(B4l + 16384);                 // N*128 fp32, in-place L1-L3
    unsigned short* gnA = (unsigned short*)(gs + (size_t)N_NODES * 128); // N*128 bf16
    unsigned short* gnB = gnA + (size_t)N_NODES * 128; // N*128 bf16
    float* gs4 = (float*)gnB;                          // aliases gnB (free at L4)
    unsigned short* gn4 = gnB + (size_t)N_NODES * 128; // N*64 bf16

    prep_Bsw<<<(65536 + 255) / 256, 256, 0, stream>>>(W1, B1h, B1l, 256, 128);
    prep_Bsw<<<(32768 + 255) / 256, 256, 0, stream>>>(W2, B2h, B2l, 128, 128);
    prep_Bsw<<<(32768 + 255) / 256, 256, 0, stream>>>(W3, B3h, B3l, 128, 128);
    prep_Bsw<<<(16384 + 255) / 256, 256, 0, stream>>>(W4, B4h, B4l, 128, 64);

    const int grid32 = (N_NODES + 31) / 32;   // 3125

    gemm1<<<grid32, 256, 0, stream>>>(features, B1h, B1l, gs, gnA, N_NODES);
    fused_layer<256><<<grid32, 256, 0, stream>>>(gs, gnA, neigh, B2h, B2l, gs, gnB, N_NODES);
    fused_layer<256><<<grid32, 256, 0, stream>>>(gs, gnB, neigh, B3h, B3l, gs, gnA, N_NODES);
    fused_layer<128><<<grid32, 256, 0, stream>>>(gs, gnA, neigh, B4h, B4l, gs4, gn4, N_NODES);
    agg_out<<<(N_NODES + 31) / 32, 256, 0, stream>>>(gs4, gn4, neigh, nodes, out, N_NODES);
}

// Round 7
// 476.447 us; speedup vs baseline: 1.0164x; 1.0164x over previous
//
#include <hip/hip_runtime.h>
#include <hip/hip_bf16.h>

// GraphSAGE R12: MLP-depth gather. R9-R11 showed occupancy elasticity is
// weak; Little's law says gather throughput = in-flight bytes / latency,
// and in-flight loads are VGPR-capped (4 VGPR per uint4 result). So trade
// waves for load depth: 2 explicit batches of 16 in-flight loads (64 VGPR
// data) per thread, launch_bounds(256,3) so the allocator never throttles
// scheduling (R8/R11 lesson: AGPR shares the 512 budget; bound*(V+A)<=512).
// In-flight data regs/SIMD ~3 waves x 64 = 192 vs R10's ~108.
// gemm1 keeps R11 32-row tile (measured neutral). agg_out gets the same
// batched gather. Spill falsifier: WRITE_SIZE >> 75MB.

constexpr int N_NODES = 100000;
constexpr int FANOUT  = 16;

typedef __attribute__((ext_vector_type(8))) short short8;
typedef __attribute__((ext_vector_type(4))) float f32x4;

__device__ inline unsigned short bf16_rne(float f) {
    unsigned u = __float_as_uint(f);
    return (unsigned short)((u + 0x7fffu + ((u >> 16) & 1u)) >> 16);
}
__device__ inline float bf16_tof(unsigned short s) {
    return __uint_as_float(((unsigned)s) << 16);
}

// ---- weights -> hi/lo bf16, FRAGMENT-SWIZZLED layout ----
// off(c,k) = ((tk*(C/16)+tc)*64 + qk*16 + mlc)*8 + e
//   tc=c>>4, mlc=c&15, tk=k>>5, qk=(k>>3)&3, e=k&7
__global__ __launch_bounds__(256)
void prep_Bsw(const float* __restrict__ W, unsigned short* __restrict__ Bhi,
              unsigned short* __restrict__ Blo, int D_IN, int D_OUT)
{
    int i = blockIdx.x * 256 + threadIdx.x;
    int total = 2 * D_OUT * D_IN;
    if (i >= total) return;
    int K = D_IN, C = 2 * D_OUT;
    int c = i / K, k = i % K;
    float v = (c < D_OUT) ? W[(size_t)c * (2 * K) + k]
                          : W[(size_t)(c - D_OUT) * (2 * K) + K + k];
    int tc = c >> 4, mlc = c & 15;
    int tk = k >> 5, qk = (k >> 3) & 3, e = k & 7;
    size_t off = ((size_t)(tk * (C / 16) + tc) * 64 + qk * 16 + mlc) * 8 + e;
    unsigned short hi = bf16_rne(v);
    Bhi[off] = hi;
    Blo[off] = bf16_rne(v - bf16_tof(hi));
}

// ---- gemm1: dense, K=256, C=256. block = 32 nodes, wave tile 32x64. ----
// (R11 form, measured neutral vs 64-row: pipelined A staging, swizzled B)
__global__ __launch_bounds__(256, 6)
void gemm1(const float* __restrict__ hf,
           const unsigned short* __restrict__ Bhi,
           const unsigned short* __restrict__ Blo,
           float* __restrict__ gs, unsigned short* __restrict__ gn, int N)
{
    constexpr int K = 256, DO = 128, LDA = 40;
    __shared__ unsigned short Ah[32 * LDA], Al[32 * LDA];

    const int tid  = threadIdx.x;
    const int wave = tid >> 6;
    const int lane = tid & 63;
    const int ml   = lane & 15;
    const int quad = lane >> 4;
    const int node0 = blockIdx.x * 32;

    const int srow = tid >> 3;
    const int sc4  = tid & 7;
    int nd = node0 + srow; if (nd >= N) nd = N - 1;
    const float* pA = &hf[(size_t)nd * K + sc4 * 4];

    f32x4 acc[2][4];
    #pragma unroll
    for (int mi = 0; mi < 2; ++mi)
        #pragma unroll
        for (int ni = 0; ni < 4; ++ni)
            acc[mi][ni] = (f32x4){0.f, 0.f, 0.f, 0.f};

    float4 pf = *(const float4*)&pA[0];

    for (int k0 = 0; k0 < K; k0 += 32) {
        {
            float vv[4] = {pf.x, pf.y, pf.z, pf.w};
            unsigned short hi[4], lo[4];
            #pragma unroll
            for (int e = 0; e < 4; ++e) {
                hi[e] = bf16_rne(vv[e]);
                lo[e] = bf16_rne(vv[e] - bf16_tof(hi[e]));
            }
            *(uint2*)&Ah[srow * LDA + sc4 * 4] = *(const uint2*)hi;
            *(uint2*)&Al[srow * LDA + sc4 * 4] = *(const uint2*)lo;
        }
        if (k0 + 32 < K) pf = *(const float4*)&pA[k0 + 32];
        __syncthreads();

        short8 afh[2], afl[2];
        #pragma unroll
        for (int mi = 0; mi < 2; ++mi) {
            int r = mi * 16 + ml;
            afh[mi] = *(const short8*)&Ah[r * LDA + quad * 8];
            afl[mi] = *(const short8*)&Al[r * LDA + quad * 8];
        }
        const size_t bbase = (size_t)((k0 >> 5) * 16 + wave * 4) * 512 + (size_t)lane * 8;
        #pragma unroll
        for (int ni = 0; ni < 4; ++ni) {
            short8 bh = *(const short8*)&Bhi[bbase + ni * 512];
            short8 bl = *(const short8*)&Blo[bbase + ni * 512];
            #pragma unroll
            for (int mi = 0; mi < 2; ++mi) {
                acc[mi][ni] = __builtin_amdgcn_mfma_f32_16x16x32_bf16(afl[mi], bh, acc[mi][ni], 0, 0, 0);
                acc[mi][ni] = __builtin_amdgcn_mfma_f32_16x16x32_bf16(afh[mi], bl, acc[mi][ni], 0, 0, 0);
                acc[mi][ni] = __builtin_amdgcn_mfma_f32_16x16x32_bf16(afh[mi], bh, acc[mi][ni], 0, 0, 0);
            }
        }
        __syncthreads();
    }

    #pragma unroll
    for (int mi = 0; mi < 2; ++mi)
        #pragma unroll
        for (int r = 0; r < 4; ++r) {
            int node = node0 + mi * 16 + quad * 4 + r;
            if (node >= N) continue;
            #pragma unroll
            for (int ni = 0; ni < 4; ++ni) {
                int c = wave * 64 + ni * 16 + ml;
                float v = acc[mi][ni][r];
                if (c < DO) gs[(size_t)node * DO + c] = v;
                else        gn[(size_t)node * DO + (c - DO)] = bf16_rne(v);
            }
        }
}

// ---- fused layer: 32 nodes/block, deep-MLP gather ----
// D_IN=128 fixed. C=256 (DO=128, NI=4) or C=128 (DO=64, NI=2).
template<int C>
__global__ __launch_bounds__(256, 3)
void fused_layer(const float* __restrict__ gs_in,
                 const unsigned short* __restrict__ gn_in,
                 const int* __restrict__ neigh,
                 const unsigned short* __restrict__ Bhi,
                 const unsigned short* __restrict__ Blo,
                 float* __restrict__ gs_out,
                 unsigned short* __restrict__ gn_out, int N)
{
    constexpr int K = 128, DO = C / 2, NI = C / 64;
    __shared__ unsigned short Afh[32 * 128], Afl[32 * 128];   // 16384 B total

    const int tid  = threadIdx.x;
    const int wave = tid >> 6;
    const int lane = tid & 63;
    const int ml   = lane & 15;
    const int quad = lane >> 4;
    const int node0 = blockIdx.x * 32;

    // ---- A-phase: h = relu(gs + mean*gn[nb]); 8 threads/row, thread s
    // owns chunks c0=64(s>>2)+8(s&3), c1=c0+32 (quad = one full 64B line).
    // 2 batches of 8 neighbors: 16 uint4 loads (64 VGPR) in flight each.
    {
        const int row = tid >> 3;          // node within block (0..31)
        const int s   = tid & 7;
        const int c0  = 64 * (s >> 2) + 8 * (s & 3);
        const int c1  = c0 + 32;
        int nd = node0 + row; if (nd >= N) nd = N - 1;
        const int4* nb4 = (const int4*)(neigh + (size_t)nd * FANOUT);
        int4 q0 = nb4[0], q1 = nb4[1], q2 = nb4[2], q3 = nb4[3];
        int ids[FANOUT] = {q0.x, q0.y, q0.z, q0.w, q1.x, q1.y, q1.z, q1.w,
                           q2.x, q2.y, q2.z, q2.w, q3.x, q3.y, q3.z, q3.w};
        float acc[16];
        #pragma unroll
        for (int c = 0; c < 16; ++c) acc[c] = 0.f;
        #pragma unroll
        for (int g = 0; g < 2; ++g) {
            uint4 qa[8], qb[8];
            #pragma unroll
            for (int j = 0; j < 8; ++j) {
                const uint4* src = (const uint4*)&gn_in[(size_t)ids[g * 8 + j] * 128];
                qa[j] = src[c0 >> 3];
                qb[j] = src[c1 >> 3];
            }
            #pragma unroll
            for (int j = 0; j < 8; ++j) {
                acc[0]  += __uint_as_float(qa[j].x << 16);
                acc[1]  += __uint_as_float(qa[j].x & 0xffff0000u);
                acc[2]  += __uint_as_float(qa[j].y << 16);
                acc[3]  += __uint_as_float(qa[j].y & 0xffff0000u);
                acc[4]  += __uint_as_float(qa[j].z << 16);
                acc[5]  += __uint_as_float(qa[j].z & 0xffff0000u);
                acc[6]  += __uint_as_float(qa[j].w << 16);
                acc[7]  += __uint_as_float(qa[j].w & 0xffff0000u);
                acc[8]  += __uint_as_float(qb[j].x << 16);
                acc[9]  += __uint_as_float(qb[j].x & 0xffff0000u);
                acc[10] += __uint_as_float(qb[j].y << 16);
                acc[11] += __uint_as_float(qb[j].y & 0xffff0000u);
                acc[12] += __uint_as_float(qb[j].z << 16);
                acc[13] += __uint_as_float(qb[j].z & 0xffff0000u);
                acc[14] += __uint_as_float(qb[j].w << 16);
                acc[15] += __uint_as_float(qb[j].w & 0xffff0000u);
            }
        }
        const float inv = 1.0f / (float)FANOUT;
        const float* gsp = &gs_in[(size_t)nd * 128];
        #pragma unroll
        for (int cc = 0; cc < 2; ++cc) {
            const int ch = cc ? c1 : c0;
            float4 g0 = *(const float4*)&gsp[ch];
            float4 g1 = *(const float4*)&gsp[ch + 4];
            float sv[8] = {g0.x, g0.y, g0.z, g0.w, g1.x, g1.y, g1.z, g1.w};
            alignas(16) unsigned short th[8], tl[8];
            #pragma unroll
            for (int e = 0; e < 8; ++e) {
                float h = fmaxf(fmaf(acc[cc * 8 + e], inv, sv[e]), 0.f);
                unsigned short hi = bf16_rne(h);
                th[e] = hi;
                tl[e] = bf16_rne(h - bf16_tof(hi));
            }
            int soff = (row * 128 + ch) ^ ((row & 7) << 3);
            *(uint4*)&Afh[soff] = *(const uint4*)th;
            *(uint4*)&Afl[soff] = *(const uint4*)tl;
        }
    }
    __syncthreads();

    f32x4 acc[2][NI];
    #pragma unroll
    for (int mi = 0; mi < 2; ++mi)
        #pragma unroll
        for (int ni = 0; ni < NI; ++ni)
            acc[mi][ni] = (f32x4){0.f, 0.f, 0.f, 0.f};

    // barrier-free k-loop: A from swizzled LDS, B fragment-swizzled global
    for (int k0 = 0; k0 < K; k0 += 32) {
        short8 afh[2], afl[2];
        #pragma unroll
        for (int mi = 0; mi < 2; ++mi) {
            int r = mi * 16 + ml;
            int soff = (r * 128 + k0 + quad * 8) ^ ((r & 7) << 3);
            afh[mi] = *(const short8*)&Afh[soff];
            afl[mi] = *(const short8*)&Afl[soff];
        }
        const size_t bbase = (size_t)((k0 >> 5) * (C / 16) + wave * NI) * 512 + (size_t)lane * 8;
        #pragma unroll
        for (int ni = 0; ni < NI; ++ni) {
            short8 bh = *(const short8*)&Bhi[bbase + ni * 512];
            short8 bl = *(const short8*)&Blo[bbase + ni * 512];
            #pragma unroll
            for (int mi = 0; mi < 2; ++mi) {
                acc[mi][ni] = __builtin_amdgcn_mfma_f32_16x16x32_bf16(afl[mi], bh, acc[mi][ni], 0, 0, 0);
                acc[mi][ni] = __builtin_amdgcn_mfma_f32_16x16x32_bf16(afh[mi], bl, acc[mi][ni], 0, 0, 0);
                acc[mi][ni] = __builtin_amdgcn_mfma_f32_16x16x32_bf16(afh[mi], bh, acc[mi][ni], 0, 0, 0);
            }
        }
    }

    #pragma unroll
    for (int mi = 0; mi < 2; ++mi)
        #pragma unroll
        for (int r = 0; r < 4; ++r) {
            int node = node0 + mi * 16 + quad * 4 + r;
            if (node >= N) continue;
            #pragma unroll
            for (int ni = 0; ni < NI; ++ni) {
                int c = wave * (16 * NI) + ni * 16 + ml;
                float v = acc[mi][ni][r];
                if (c < DO) gs_out[(size_t)node * DO + c] = v;
                else        gn_out[(size_t)node * DO + (c - DO)] = bf16_rne(v);
            }
        }
}

// ---- final: out[i] = relu(gs4[nodes[i]] + mean_j gn4[nb[j]]), D_OUT=64 ----
// Batched gather: all 16 uint4 loads (64 VGPR) in flight, then accumulate.
__global__ __launch_bounds__(256, 3)
void agg_out(const float* __restrict__ gs4, const unsigned short* __restrict__ gn4,
             const int* __restrict__ neigh, const int* __restrict__ nodes,
             float* __restrict__ out, int N)
{
    const int i    = blockIdx.x * 32 + (threadIdx.x >> 3);
    const int lane = threadIdx.x & 7;
    if (i >= N) return;
    const int nd = nodes[i];
    const int4* nb4 = (const int4*)(neigh + (size_t)nd * FANOUT);
    int4 q0 = nb4[0], q1 = nb4[1], q2 = nb4[2], q3 = nb4[3];
    int ids[FANOUT] = {q0.x, q0.y, q0.z, q0.w, q1.x, q1.y, q1.z, q1.w,
                       q2.x, q2.y, q2.z, q2.w, q3.x, q3.y, q3.z, q3.w};
    uint4 qv[FANOUT];
    #pragma unroll
    for (int j = 0; j < FANOUT; ++j)
        qv[j] = *(const uint4*)&gn4[(size_t)ids[j] * 64 + lane * 8];
    float acc[8];
    #pragma unroll
    for (int c = 0; c < 8; ++c) acc[c] = 0.f;
    #pragma unroll
    for (int j = 0; j < FANOUT; ++j) {
        acc[0] += __uint_as_float(qv[j].x << 16);
        acc[1] += __uint_as_float(qv[j].x & 0xffff0000u);
        acc[2] += __uint_as_float(qv[j].y << 16);
        acc[3] += __uint_as_float(qv[j].y & 0xffff0000u);
        acc[4] += __uint_as_float(qv[j].z << 16);
        acc[5] += __uint_as_float(qv[j].z & 0xffff0000u);
        acc[6] += __uint_as_float(qv[j].w << 16);
        acc[7] += __uint_as_float(qv[j].w & 0xffff0000u);
    }
    const float inv = 1.0f / (float)FANOUT;
    const float* s = gs4 + (size_t)nd * 64 + lane * 8;
    float4 s0 = *(const float4*)&s[0];
    float4 s1 = *(const float4*)&s[4];
    float4 o0, o1;
    o0.x = fmaxf(fmaf(acc[0], inv, s0.x), 0.f);
    o0.y = fmaxf(fmaf(acc[1], inv, s0.y), 0.f);
    o0.z = fmaxf(fmaf(acc[2], inv, s0.z), 0.f);
    o0.w = fmaxf(fmaf(acc[3], inv, s0.w), 0.f);
    o1.x = fmaxf(fmaf(acc[4], inv, s1.x), 0.f);
    o1.y = fmaxf(fmaf(acc[5], inv, s1.y), 0.f);
    o1.z = fmaxf(fmaf(acc[6], inv, s1.z), 0.f);
    o1.w = fmaxf(fmaf(acc[7], inv, s1.w), 0.f);
    float* op = out + (size_t)i * 64 + lane * 8;
    *(float4*)&op[0] = o0;
    *(float4*)&op[4] = o1;
}

extern "C" void kernel_launch(void* const* d_in, const int* in_sizes, int n_in,
                              void* d_out, int out_size, void* d_ws, size_t ws_size,
                              hipStream_t stream)
{
    const float* features = (const float*)d_in[0];
    const float* W1       = (const float*)d_in[1];
    const float* W2       = (const float*)d_in[2];
    const float* W3       = (const float*)d_in[3];
    const float* W4       = (const float*)d_in[4];
    const int*   nodes    = (const int*)d_in[5];
    const int*   neigh    = (const int*)d_in[6];
    float*       out      = (float*)d_out;

    unsigned short* B1h = (unsigned short*)d_ws;       // 65536
    unsigned short* B1l = B1h + 65536;
    unsigned short* B2h = B1l + 65536;                 // 32768
    unsigned short* B2l = B2h + 32768;
    unsigned short* B3h = B2l + 32768;
    unsigned short* B3l = B3h + 32768;
    unsigned short* B4h = B3l + 32768;                 // 16384
    unsigned short* B4l = B4h + 16384;
    float* gs = (float*)(B4l + 16384);                 // N*128 fp32, in-place L1-L3
    unsigned short* gnA = (unsigned short*)(gs + (size_t)N_NODES * 128); // N*128 bf16
    unsigned short* gnB = gnA + (size_t)N_NODES * 128; // N*128 bf16
    float* gs4 = (float*)gnB;                          // aliases gnB (free at L4)
    unsigned short* gn4 = gnB + (size_t)N_NODES * 128; // N*64 bf16

    prep_Bsw<<<(65536 + 255) / 256, 256, 0, stream>>>(W1, B1h, B1l, 256, 128);
    prep_Bsw<<<(32768 + 255) / 256, 256, 0, stream>>>(W2, B2h, B2l, 128, 128);
    prep_Bsw<<<(32768 + 255) / 256, 256, 0, stream>>>(W3, B3h, B3l, 128, 128);
    prep_Bsw<<<(16384 + 255) / 256, 256, 0, stream>>>(W4, B4h, B4l, 128, 64);

    const int grid32 = (N_NODES + 31) / 32;   // 3125

    gemm1<<<grid32, 256, 0, stream>>>(features, B1h, B1l, gs, gnA, N_NODES);
    fused_layer<256><<<grid32, 256, 0, stream>>>(gs, gnA, neigh, B2h, B2l, gs, gnB, N_NODES);
    fused_layer<256><<<grid32, 256, 0, stream>>>(gs, gnB, neigh, B3h, B3l, gs, gnA, N_NODES);
    fused_layer<128><<<grid32, 256, 0, stream>>>(gs, gnA, neigh, B4h, B4l, gs4, gn4, N_NODES);
    agg_out<<<(N_NODES + 31) / 32, 256, 0, stream>>>(gs4, gn4, neigh, nodes, out, N_NODES);
}